// Round 1
// baseline (1056.453 us; speedup 1.0000x reference)
//
#include <hip/hip_runtime.h>
#include <hip/hip_bf16.h>
#include <math.h>

// Problem constants (from reference setup_inputs):
// B=4, N=4096, k=32, Cin=64, Cout=64, M=8, hidden=16
#define PB 4
#define PN 4096
#define PK 32
#define NKP (PN * PK)              // 131072 points per batch
#define PTOT (PB * NKP)            // 524288 total points
#define CIN 64
#define COUT 64
#define PM 8
#define HID 16
#define EPS 1e-5f

// ws float layout:
//  [0..13]    xyz moments: sums of (x,y,z,ed) then upper-tri second moments (10)
//  [16..31]   alpha1 (BN1 folded scale)
//  [32..47]   beta1  (BN1 folded shift)
//  [64..127]  out channel sums
//  [128..191] out channel sumsq
//  [192..255] alpha2
//  [256..319] beta2
#define WS_MOM 0
#define WS_A1 16
#define WS_B1 32
#define WS_SUM 64
#define WS_SQ 128
#define WS_A2 192
#define WS_B2 256
#define WS_FLOATS 320

// ---------------------------------------------------------------------------
// Kernel 1: reduce first and second moments of [x, y, z, ||xyz||] over all
// points. BN1's pre-activation t = w1 @ v is linear in v, so per-channel
// mean/var derive from these 14 scalars (avoids materializing the hidden
// tensor).
// ---------------------------------------------------------------------------
__global__ __launch_bounds__(256) void k_xyz_moments(
    const float* __restrict__ gx, float* __restrict__ mom) {
  float s[14];
#pragma unroll
  for (int i = 0; i < 14; ++i) s[i] = 0.f;

  int tid = blockIdx.x * blockDim.x + threadIdx.x;
  int stride = gridDim.x * blockDim.x;
  for (int p = tid; p < PTOT; p += stride) {
    int b = p >> 17;          // / NKP
    int r = p & (NKP - 1);
    const float* base = gx + (size_t)b * 3 * NKP + r;
    float v[4];
    v[0] = base[0];
    v[1] = base[NKP];
    v[2] = base[2 * NKP];
    v[3] = sqrtf(v[0] * v[0] + v[1] * v[1] + v[2] * v[2]);
#pragma unroll
    for (int j = 0; j < 4; ++j) s[j] += v[j];
    int idx = 4;
#pragma unroll
    for (int j = 0; j < 4; ++j)
#pragma unroll
      for (int l = j; l < 4; ++l) s[idx++] += v[j] * v[l];
  }

  // wave64 reduce each scalar
#pragma unroll
  for (int i = 0; i < 14; ++i) {
    float x = s[i];
#pragma unroll
    for (int off = 32; off > 0; off >>= 1) x += __shfl_down(x, off, 64);
    s[i] = x;
  }
  if ((threadIdx.x & 63) == 0) {
#pragma unroll
    for (int i = 0; i < 14; ++i) atomicAdd(&mom[i], s[i]);
  }
}

// ---------------------------------------------------------------------------
// Kernel 2: fold BN1 into per-channel affine alpha1/beta1 (16 channels).
// ---------------------------------------------------------------------------
__global__ void k_finalize1(const float* __restrict__ ws,
                            const float* __restrict__ w1,
                            const float* __restrict__ g1,
                            const float* __restrict__ b1,
                            float* __restrict__ out_ws) {
  int c = threadIdx.x;
  if (c >= HID) return;
  const float invP = 1.f / (float)PTOT;
  float mu[4];
#pragma unroll
  for (int j = 0; j < 4; ++j) mu[j] = ws[WS_MOM + j] * invP;
  float S[4][4];
  int idx = 4;
#pragma unroll
  for (int j = 0; j < 4; ++j)
#pragma unroll
    for (int l = j; l < 4; ++l) {
      float v = ws[WS_MOM + idx++] * invP;
      S[j][l] = v;
      S[l][j] = v;
    }
  float w[4];
#pragma unroll
  for (int j = 0; j < 4; ++j) w[j] = w1[c * 4 + j];
  float mean = 0.f;
#pragma unroll
  for (int j = 0; j < 4; ++j) mean += w[j] * mu[j];
  float Et2 = 0.f;
#pragma unroll
  for (int j = 0; j < 4; ++j)
#pragma unroll
    for (int l = 0; l < 4; ++l) Et2 += w[j] * w[l] * S[j][l];
  float var = Et2 - mean * mean;
  float a = g1[c] * rsqrtf(var + EPS);
  out_ws[WS_A1 + c] = a;
  out_ws[WS_B1 + c] = b1[c] - a * mean;
}

// ---------------------------------------------------------------------------
// Kernel 3: main per-point compute. One thread per point:
//   scores (ScoreNet with folded BN1) -> out[c] = sum_{ci,m} sc[m]*f[ci]*W[ci,m,c]
// restructured as acc[c] += f * (sum_m sc[m]*W[ci, m*64+c]).
// weightbank reads are wave-uniform -> scalar loads feeding v_fmac.
// Writes PRE-BN output to d_out in (B, Cout, N, k) layout.
// ---------------------------------------------------------------------------
__global__ __launch_bounds__(256) void k_main(
    const float* __restrict__ gx, const float* __restrict__ feat,
    const float* __restrict__ w1, const float* __restrict__ ws,
    const float* __restrict__ w2, const float* __restrict__ b2,
    const float* __restrict__ wb, float* __restrict__ out) {
  int p = blockIdx.x * 256 + threadIdx.x;
  if (p >= PTOT) return;
  int b = p >> 17;
  int r = p & (NKP - 1);

  // --- ScoreNet ---
  const float* base = gx + (size_t)b * 3 * NKP + r;
  float x = base[0];
  float y = base[NKP];
  float z = base[2 * NKP];
  float ed = sqrtf(x * x + y * y + z * z);

  float h[HID];
#pragma unroll
  for (int c = 0; c < HID; ++c) {
    float t = w1[c * 4 + 0] * x + w1[c * 4 + 1] * y + w1[c * 4 + 2] * z +
              w1[c * 4 + 3] * ed;
    h[c] = fmaxf(ws[WS_A1 + c] * t + ws[WS_B1 + c], 0.f);
  }
  float s[PM];
#pragma unroll
  for (int m = 0; m < PM; ++m) {
    float acc = b2[m];
#pragma unroll
    for (int c = 0; c < HID; ++c) acc += w2[m * HID + c] * h[c];
    s[m] = acc;
  }
  float mx = s[0];
#pragma unroll
  for (int m = 1; m < PM; ++m) mx = fmaxf(mx, s[m]);
  float e[PM], esum = 0.f;
#pragma unroll
  for (int m = 0; m < PM; ++m) {
    e[m] = expf(s[m] - mx);
    esum += e[m];
  }
  float inv = 1.f / (1.f + esum);
  float sc[PM];
#pragma unroll
  for (int m = 0; m < PM; ++m) sc[m] = e[m] * inv;

  // --- weightbank projection + score combine ---
  float acc[COUT];
#pragma unroll
  for (int c = 0; c < COUT; ++c) acc[c] = 0.f;

  const float* fbase = feat + (size_t)b * CIN * NKP + r;
  for (int ci = 0; ci < CIN; ++ci) {
    float f = fbase[(size_t)ci * NKP];
    const float* wrow = wb + ci * (PM * COUT);
#pragma unroll
    for (int c = 0; c < COUT; ++c) {
      float wc = 0.f;
#pragma unroll
      for (int m = 0; m < PM; ++m) wc = fmaf(sc[m], wrow[m * COUT + c], wc);
      acc[c] = fmaf(f, wc, acc[c]);
    }
  }

  float* obase = out + (size_t)b * COUT * NKP + r;
#pragma unroll
  for (int c = 0; c < COUT; ++c) obase[(size_t)c * NKP] = acc[c];
}

// ---------------------------------------------------------------------------
// Kernel 4: per-channel sum/sumsq over the pre-BN output.
// One block per (b, c) slab of 131072 contiguous floats.
// ---------------------------------------------------------------------------
__global__ __launch_bounds__(256) void k_outstats(const float* __restrict__ out,
                                                  float* __restrict__ ws) {
  int slab = blockIdx.x;  // b*64 + c
  int c = slab & 63;
  const float4* p4 = (const float4*)(out + (size_t)slab * NKP);
  float s = 0.f, q = 0.f;
  for (int i = threadIdx.x; i < NKP / 4; i += 256) {
    float4 v = p4[i];
    s += v.x + v.y + v.z + v.w;
    q += v.x * v.x + v.y * v.y + v.z * v.z + v.w * v.w;
  }
#pragma unroll
  for (int off = 32; off > 0; off >>= 1) {
    s += __shfl_down(s, off, 64);
    q += __shfl_down(q, off, 64);
  }
  __shared__ float red[8];
  int wave = threadIdx.x >> 6;
  if ((threadIdx.x & 63) == 0) {
    red[wave] = s;
    red[4 + wave] = q;
  }
  __syncthreads();
  if (threadIdx.x == 0) {
    float S = red[0] + red[1] + red[2] + red[3];
    float Q = red[4] + red[5] + red[6] + red[7];
    atomicAdd(&ws[WS_SUM + c], S);
    atomicAdd(&ws[WS_SQ + c], Q);
  }
}

// ---------------------------------------------------------------------------
// Kernel 5: fold BN2 into alpha2/beta2 (64 channels).
// ---------------------------------------------------------------------------
__global__ void k_finalize2(const float* __restrict__ ws,
                            const float* __restrict__ g_out,
                            const float* __restrict__ b_out,
                            float* __restrict__ out_ws) {
  int c = threadIdx.x;
  if (c >= COUT) return;
  const float invP = 1.f / (float)PTOT;
  float mean = ws[WS_SUM + c] * invP;
  float var = ws[WS_SQ + c] * invP - mean * mean;
  float a = g_out[c] * rsqrtf(var + EPS);
  out_ws[WS_A2 + c] = a;
  out_ws[WS_B2 + c] = b_out[c] - a * mean;
}

// ---------------------------------------------------------------------------
// Kernel 6: in-place normalize + ReLU on d_out.
// ---------------------------------------------------------------------------
__global__ __launch_bounds__(256) void k_norm(float* __restrict__ out,
                                              const float* __restrict__ ws) {
  size_t i4 = (size_t)blockIdx.x * 256 + threadIdx.x;  // float4 index
  size_t elem = i4 * 4;
  int c = (int)((elem >> 17) & 63);
  float a = ws[WS_A2 + c];
  float bb = ws[WS_B2 + c];
  float4* p = (float4*)out;
  float4 v = p[i4];
  v.x = fmaxf(a * v.x + bb, 0.f);
  v.y = fmaxf(a * v.y + bb, 0.f);
  v.z = fmaxf(a * v.z + bb, 0.f);
  v.w = fmaxf(a * v.w + bb, 0.f);
  p[i4] = v;
}

extern "C" void kernel_launch(void* const* d_in, const int* in_sizes, int n_in,
                              void* d_out, int out_size, void* d_ws,
                              size_t ws_size, hipStream_t stream) {
  const float* gx = (const float*)d_in[0];      // (4,3,4096,32)
  const float* feat = (const float*)d_in[1];    // (4,64,4096,32)
  const float* w1 = (const float*)d_in[2];      // (16,4)
  const float* g1 = (const float*)d_in[3];      // (16)
  const float* b1 = (const float*)d_in[4];      // (16)
  const float* w2 = (const float*)d_in[5];      // (8,16)
  const float* b2 = (const float*)d_in[6];      // (8)
  const float* wb = (const float*)d_in[7];      // (64,512)
  const float* g_out = (const float*)d_in[8];   // (64)
  const float* b_out = (const float*)d_in[9];   // (64)
  float* out = (float*)d_out;                   // (4,64,4096,32) fp32
  float* ws = (float*)d_ws;

  (void)in_sizes; (void)n_in; (void)out_size; (void)ws_size;

  // zero the accumulator region of ws (harness poisons it with 0xAA)
  hipMemsetAsync(d_ws, 0, WS_FLOATS * sizeof(float), stream);

  k_xyz_moments<<<512, 256, 0, stream>>>(gx, ws);
  k_finalize1<<<1, 64, 0, stream>>>(ws, w1, g1, b1, ws);
  k_main<<<PTOT / 256, 256, 0, stream>>>(gx, feat, w1, ws, w2, b2, wb, out);
  k_outstats<<<PB * COUT, 256, 0, stream>>>(out, ws);
  k_finalize2<<<1, 64, 0, stream>>>(ws, g_out, b_out, ws);
  k_norm<<<(PTOT * COUT / 4) / 256, 256, 0, stream>>>(out, ws);
}

// Round 2
// 803.900 us; speedup vs baseline: 1.3142x; 1.3142x over previous
//
#include <hip/hip_runtime.h>
#include <hip/hip_bf16.h>
#include <math.h>

// Problem constants: B=4, N=4096, k=32, Cin=64, Cout=64, M=8, hidden=16
#define PB 4
#define PN 4096
#define PK 32
#define NKP (PN * PK)              // 131072 points per batch (2^17)
#define PTOT (PB * NKP)            // 524288 total points
#define CIN 64
#define COUT 64
#define PM 8
#define HID 16
#define EPS 1e-5f

// ws float layout
#define WS_MOM 0            // 14 floats: xyz moment sums
#define WS_A1 16            // 16: BN1 folded scale
#define WS_B1 32            // 16: BN1 folded shift
#define WS_A2 64            // 64: BN2 folded scale
#define WS_B2 128           // 64: BN2 folded shift
#define WS_PSUM 256         // 32 slots x 64: out channel sum partials
#define WS_PSQ 2304         // 32 slots x 64: out channel sumsq partials
#define WS_ZERO_FLOATS 4608
#define WS_WBT 4608         // bf16 wbT[512][64] as ushort (32768 entries, 64 KB)

typedef __attribute__((ext_vector_type(8))) short short8;
typedef __attribute__((ext_vector_type(4))) float float4v;
typedef __attribute__((ext_vector_type(4))) unsigned short ushort4v;
typedef unsigned int uint32;
typedef unsigned short ushort16;

// fp32 -> bf16 with round-half-up (cheap: add 0x8000, take hi16)
static __device__ __forceinline__ ushort16 f2bf(float v) {
  uint32 u = __builtin_bit_cast(uint32, v);
  return (ushort16)((u + 0x8000u) >> 16);
}

// ---------------------------------------------------------------------------
// Kernel 1: first/second moments of [x,y,z,||xyz||] (BN1 is linear in these).
// ---------------------------------------------------------------------------
__global__ __launch_bounds__(256) void k_xyz_moments(
    const float* __restrict__ gx, float* __restrict__ mom) {
  float s[14];
#pragma unroll
  for (int i = 0; i < 14; ++i) s[i] = 0.f;
  int tid = blockIdx.x * blockDim.x + threadIdx.x;
  int stride = gridDim.x * blockDim.x;
  for (int p = tid; p < PTOT; p += stride) {
    int b = p >> 17;
    int r = p & (NKP - 1);
    const float* base = gx + (size_t)b * 3 * NKP + r;
    float v[4];
    v[0] = base[0];
    v[1] = base[NKP];
    v[2] = base[2 * NKP];
    v[3] = sqrtf(v[0] * v[0] + v[1] * v[1] + v[2] * v[2]);
#pragma unroll
    for (int j = 0; j < 4; ++j) s[j] += v[j];
    int idx = 4;
#pragma unroll
    for (int j = 0; j < 4; ++j)
#pragma unroll
      for (int l = j; l < 4; ++l) s[idx++] += v[j] * v[l];
  }
#pragma unroll
  for (int i = 0; i < 14; ++i) {
    float x = s[i];
#pragma unroll
    for (int off = 32; off > 0; off >>= 1) x += __shfl_down(x, off, 64);
    s[i] = x;
  }
  if ((threadIdx.x & 63) == 0) {
#pragma unroll
    for (int i = 0; i < 14; ++i) atomicAdd(&mom[i], s[i]);
  }
}

// ---------------------------------------------------------------------------
// Kernel 2: transpose wb (64x512 fp32) -> wbT bf16 [col=512][ci=64] in ws.
// Reads coalesced; writes scattered but tiny (64 KB total, one-shot).
// ---------------------------------------------------------------------------
__global__ __launch_bounds__(256) void k_wbt(const float* __restrict__ wb,
                                             ushort16* __restrict__ wbt) {
  int idx = blockIdx.x * 256 + threadIdx.x;  // 0..32767 = ci*512 + col
  int ci = idx >> 9;
  int col = idx & 511;
  wbt[col * 64 + ci] = f2bf(wb[idx]);
}

// ---------------------------------------------------------------------------
// Kernel 3: fold BN1 into alpha1/beta1 from the 14 moments.
// ---------------------------------------------------------------------------
__global__ void k_finalize1(const float* __restrict__ ws,
                            const float* __restrict__ w1,
                            const float* __restrict__ g1,
                            const float* __restrict__ b1,
                            float* __restrict__ out_ws) {
  int c = threadIdx.x;
  if (c >= HID) return;
  const float invP = 1.f / (float)PTOT;
  float mu[4];
#pragma unroll
  for (int j = 0; j < 4; ++j) mu[j] = ws[WS_MOM + j] * invP;
  float S[4][4];
  int idx = 4;
#pragma unroll
  for (int j = 0; j < 4; ++j)
#pragma unroll
    for (int l = j; l < 4; ++l) {
      float v = ws[WS_MOM + idx++] * invP;
      S[j][l] = v;
      S[l][j] = v;
    }
  float w[4];
#pragma unroll
  for (int j = 0; j < 4; ++j) w[j] = w1[c * 4 + j];
  float mean = 0.f;
#pragma unroll
  for (int j = 0; j < 4; ++j) mean += w[j] * mu[j];
  float Et2 = 0.f;
#pragma unroll
  for (int j = 0; j < 4; ++j)
#pragma unroll
    for (int l = 0; l < 4; ++l) Et2 += w[j] * w[l] * S[j][l];
  float var = Et2 - mean * mean;
  float a = g1[c] * rsqrtf(var + EPS);
  out_ws[WS_A1 + c] = a;
  out_ws[WS_B1 + c] = b1[c] - a * mean;
}

// ---------------------------------------------------------------------------
// Kernel 4: main MFMA kernel. 128 points/block, 256 threads (4 waves),
// each wave owns 32 rows (2 rowtiles of 16) x 64 out channels (4 coltiles).
// out[p,c] = sum_m sum_ci (sc[p,m]*f[p,ci]) * wbT[m*64+c][ci]
// A = score-scaled bf16 feat fragments (scaled per m in registers),
// B = wbT fragments loaded straight from global (L2-resident 64 KB).
// Fuses BN2 stats (register shfl reduce -> spread atomic partials).
// Writes pre-BN fp32 out via LDS transpose for coalesced stores.
// ---------------------------------------------------------------------------
#define PPB 128   // points per block
#define ROWA 68   // feat LDS row pitch (bf16 units; 136 B keeps b64 align)
#define ROWO 66   // out-stage LDS row pitch (floats)

__global__ __launch_bounds__(256, 3) void k_main_mfma(
    const float* __restrict__ gx, const float* __restrict__ feat,
    const float* __restrict__ w1, const float* __restrict__ w2,
    const float* __restrict__ b2, const ushort16* __restrict__ wbt,
    float* __restrict__ ws, float* __restrict__ out) {
  __shared__ char smem[35840];
  ushort16* fl = (ushort16*)smem;              // phase1: [128][ROWA] bf16
  float* scl = (float*)(smem + 17408);         // phase1: [128][8] scores
  float* outst = (float*)smem;                 // phase2: [128][ROWO] fp32
  float* sstat = (float*)(smem + 33792);       // phase2: [4][64]
  float* qstat = (float*)(smem + 34816);       // phase2: [4][64]

  const int t = threadIdx.x;
  const int pblk = blockIdx.x * PPB;
  const int b = pblk >> 17;
  const int r0 = pblk & (NKP - 1);

  // ---- Phase 1a: ScoreNet for the block's 128 points (threads 0..127)
  if (t < PPB) {
    int r = r0 + t;
    const float* gb = gx + (size_t)b * 3 * NKP + r;
    float x = gb[0], y = gb[NKP], z = gb[2 * NKP];
    float ed = sqrtf(x * x + y * y + z * z);
    float h[HID];
#pragma unroll
    for (int c = 0; c < HID; ++c) {
      float tv = w1[c * 4 + 0] * x + w1[c * 4 + 1] * y + w1[c * 4 + 2] * z +
                 w1[c * 4 + 3] * ed;
      h[c] = fmaxf(ws[WS_A1 + c] * tv + ws[WS_B1 + c], 0.f);
    }
    float s[PM];
#pragma unroll
    for (int m = 0; m < PM; ++m) {
      float a = b2[m];
#pragma unroll
      for (int c = 0; c < HID; ++c) a += w2[m * HID + c] * h[c];
      s[m] = a;
    }
    float mx = s[0];
#pragma unroll
    for (int m = 1; m < PM; ++m) mx = fmaxf(mx, s[m]);
    float esum = 0.f;
#pragma unroll
    for (int m = 0; m < PM; ++m) {
      s[m] = __expf(s[m] - mx);
      esum += s[m];
    }
    float inv = 1.f / (1.f + esum);
#pragma unroll
    for (int m = 0; m < PM; ++m) scl[t * 8 + m] = s[m] * inv;
  }

  // ---- Phase 1b: stage feat tile to LDS as bf16, transposed to [p][ci]
  {
    const float* fb = feat + (size_t)b * CIN * NKP + r0;
#pragma unroll
    for (int i = 0; i < 32; ++i) {
      int flat = i * 256 + t;
      int p = flat & (PPB - 1);
      int ci = flat >> 7;
      fl[p * ROWA + ci] = f2bf(fb[(size_t)ci * NKP + p]);
    }
  }
  __syncthreads();

  const int w = t >> 6;
  const int L = t & 63;
  const int l16 = L & 15;
  const int q4 = L >> 4;

  // preload f fragments (unpacked fp32 for cheap per-m scaling) + scores
  float ff[2][2][8];  // [rowtile][kstep][elem]
#pragma unroll
  for (int rt = 0; rt < 2; ++rt) {
    int p = w * 32 + rt * 16 + l16;
#pragma unroll
    for (int ks = 0; ks < 2; ++ks) {
      const ushort4v* a0 = (const ushort4v*)&fl[p * ROWA + ks * 32 + q4 * 8];
      ushort4v v0 = a0[0], v1 = a0[1];
#pragma unroll
      for (int j = 0; j < 4; ++j) {
        ff[rt][ks][j] = __builtin_bit_cast(float, (uint32)v0[j] << 16);
        ff[rt][ks][4 + j] = __builtin_bit_cast(float, (uint32)v1[j] << 16);
      }
    }
  }
  float4v scf[2][2];  // [rowtile][half]: 8 scores for this lane's row
#pragma unroll
  for (int rt = 0; rt < 2; ++rt) {
    int p = w * 32 + rt * 16 + l16;
    const float4v* sp = (const float4v*)&scl[p * 8];
    scf[rt][0] = sp[0];
    scf[rt][1] = sp[1];
  }

  float4v acc[2][4];
#pragma unroll
  for (int rt = 0; rt < 2; ++rt)
#pragma unroll
    for (int ct = 0; ct < 4; ++ct) acc[rt][ct] = (float4v)0.f;

  // ---- m loop: scale A by sc[p][m], MFMA against wbT m-slice
#pragma unroll
  for (int m = 0; m < PM; ++m) {
    short8 bf[2][4];  // [kstep][coltile]
#pragma unroll
    for (int ks = 0; ks < 2; ++ks)
#pragma unroll
      for (int ct = 0; ct < 4; ++ct) {
        int col = m * 64 + ct * 16 + l16;
        bf[ks][ct] = *(const short8*)(wbt + col * 64 + ks * 32 + q4 * 8);
      }
#pragma unroll
    for (int rt = 0; rt < 2; ++rt) {
      float sm = scf[rt][m >> 2][m & 3];
#pragma unroll
      for (int ks = 0; ks < 2; ++ks) {
        union { short8 v; uint32 u[4]; } au;
#pragma unroll
        for (int e = 0; e < 4; ++e) {
          uint32 u0 =
              __builtin_bit_cast(uint32, ff[rt][ks][2 * e] * sm) + 0x8000u;
          uint32 u1 =
              __builtin_bit_cast(uint32, ff[rt][ks][2 * e + 1] * sm) + 0x8000u;
          au.u[e] = __builtin_amdgcn_perm(u1, u0, 0x07060302u);
        }
#pragma unroll
        for (int ct = 0; ct < 4; ++ct)
          acc[rt][ct] = __builtin_amdgcn_mfma_f32_16x16x32_bf16(
              au.v, bf[ks][ct], acc[rt][ct], 0, 0, 0);
      }
    }
  }
  __syncthreads();  // all LDS phase-1 reads done; safe to overwrite with outst

  // ---- BN2 stats from accumulators (cols: lanes L, L^16, L^32, L^48 share c)
#pragma unroll
  for (int ct = 0; ct < 4; ++ct) {
    float s = 0.f, q = 0.f;
#pragma unroll
    for (int rt = 0; rt < 2; ++rt)
#pragma unroll
      for (int r = 0; r < 4; ++r) {
        float v = acc[rt][ct][r];
        s += v;
        q += v * v;
      }
    s += __shfl_xor(s, 16, 64);
    q += __shfl_xor(q, 16, 64);
    s += __shfl_xor(s, 32, 64);
    q += __shfl_xor(q, 32, 64);
    if (L < 16) {
      sstat[w * 64 + ct * 16 + L] = s;
      qstat[w * 64 + ct * 16 + L] = q;
    }
  }

  // ---- stage out tile [p][c] (C-layout: row=q4*4+r, col=l16)
#pragma unroll
  for (int rt = 0; rt < 2; ++rt)
#pragma unroll
    for (int ct = 0; ct < 4; ++ct) {
      int rowb = w * 32 + rt * 16 + q4 * 4;
      int col = ct * 16 + l16;
#pragma unroll
      for (int r = 0; r < 4; ++r)
        outst[(rowb + r) * ROWO + col] = acc[rt][ct][r];
    }
  __syncthreads();

  // ---- block stats reduce -> spread atomics
  if (t < COUT) {
    float s = sstat[t] + sstat[64 + t] + sstat[128 + t] + sstat[192 + t];
    float q = qstat[t] + qstat[64 + t] + qstat[128 + t] + qstat[192 + t];
    int slot = blockIdx.x & 31;
    atomicAdd(&ws[WS_PSUM + slot * 64 + t], s);
    atomicAdd(&ws[WS_PSQ + slot * 64 + t], q);
  }

  // ---- coalesced global write of pre-BN out
  float* ob = out + (size_t)b * COUT * NKP + r0;
#pragma unroll
  for (int i = 0; i < 32; ++i) {
    int flat = i * 256 + t;
    int p = flat & (PPB - 1);
    int c = flat >> 7;
    ob[(size_t)c * NKP + p] = outst[p * ROWO + c];
  }
}

// ---------------------------------------------------------------------------
// Kernel 5: fold BN2 (reduce the 32 partial slots).
// ---------------------------------------------------------------------------
__global__ void k_finalize2(const float* __restrict__ ws,
                            const float* __restrict__ g_out,
                            const float* __restrict__ b_out,
                            float* __restrict__ out_ws) {
  int c = threadIdx.x;
  if (c >= COUT) return;
  float s = 0.f, q = 0.f;
  for (int sl = 0; sl < 32; ++sl) {
    s += ws[WS_PSUM + sl * 64 + c];
    q += ws[WS_PSQ + sl * 64 + c];
  }
  const float invP = 1.f / (float)PTOT;
  float mean = s * invP;
  float var = q * invP - mean * mean;
  float a = g_out[c] * rsqrtf(var + EPS);
  out_ws[WS_A2 + c] = a;
  out_ws[WS_B2 + c] = b_out[c] - a * mean;
}

// ---------------------------------------------------------------------------
// Kernel 6: in-place normalize + ReLU.
// ---------------------------------------------------------------------------
__global__ __launch_bounds__(256) void k_norm(float* __restrict__ out,
                                              const float* __restrict__ ws) {
  size_t i4 = (size_t)blockIdx.x * 256 + threadIdx.x;
  size_t elem = i4 * 4;
  int c = (int)((elem >> 17) & 63);
  float a = ws[WS_A2 + c];
  float bb = ws[WS_B2 + c];
  float4* p = (float4*)out;
  float4 v = p[i4];
  v.x = fmaxf(a * v.x + bb, 0.f);
  v.y = fmaxf(a * v.y + bb, 0.f);
  v.z = fmaxf(a * v.z + bb, 0.f);
  v.w = fmaxf(a * v.w + bb, 0.f);
  p[i4] = v;
}

extern "C" void kernel_launch(void* const* d_in, const int* in_sizes, int n_in,
                              void* d_out, int out_size, void* d_ws,
                              size_t ws_size, hipStream_t stream) {
  const float* gx = (const float*)d_in[0];
  const float* feat = (const float*)d_in[1];
  const float* w1 = (const float*)d_in[2];
  const float* g1 = (const float*)d_in[3];
  const float* b1 = (const float*)d_in[4];
  const float* w2 = (const float*)d_in[5];
  const float* b2 = (const float*)d_in[6];
  const float* wb = (const float*)d_in[7];
  const float* g_out = (const float*)d_in[8];
  const float* b_out = (const float*)d_in[9];
  float* out = (float*)d_out;
  float* ws = (float*)d_ws;
  ushort16* wbt = (ushort16*)(ws + WS_WBT);

  (void)in_sizes; (void)n_in; (void)out_size; (void)ws_size;

  hipMemsetAsync(d_ws, 0, WS_ZERO_FLOATS * sizeof(float), stream);

  k_xyz_moments<<<512, 256, 0, stream>>>(gx, ws);
  k_wbt<<<128, 256, 0, stream>>>(wb, wbt);
  k_finalize1<<<1, 64, 0, stream>>>(ws, w1, g1, b1, ws);
  k_main_mfma<<<PTOT / PPB, 256, 0, stream>>>(gx, feat, w1, w2, b2, wbt, ws,
                                              out);
  k_finalize2<<<1, 64, 0, stream>>>(ws, g_out, b_out, ws);
  k_norm<<<(PTOT * COUT / 4) / 256, 256, 0, stream>>>(out, ws);
}

// Round 3
// 448.103 us; speedup vs baseline: 2.3576x; 1.7940x over previous
//
#include <hip/hip_runtime.h>
#include <hip/hip_bf16.h>
#include <math.h>

// Problem constants: B=4, N=4096, k=32, Cin=64, Cout=64, M=8, hidden=16
#define PB 4
#define PN 4096
#define PK 32
#define NKP (PN * PK)              // 131072 points per batch (2^17)
#define PTOT (PB * NKP)            // 524288 total points
#define CIN 64
#define COUT 64
#define PM 8
#define HID 16
#define EPS 1e-5f

// ws float layout
// Moments are PADDED: each of the 14 scalars gets its own 64B cache line so
// atomicAdds to different moments don't serialize on one line.
#define WS_MOM 0            // 14 slots x stride 16 floats = [0..224)
#define WS_A1 240           // 16: BN1 folded scale
#define WS_B1 256           // 16: BN1 folded shift
#define WS_A2 288           // 64: BN2 folded scale
#define WS_B2 352           // 64: BN2 folded shift
#define WS_PSUM 416         // 32 slots x 64: out channel sum partials
#define WS_PSQ 2464         // 32 slots x 64: out channel sumsq partials
#define WS_ZERO_FLOATS 4512
#define WS_WBT 4608         // bf16 wbT[512][64] as ushort (32768 entries, 64 KB)

typedef __attribute__((ext_vector_type(8))) short short8;
typedef __attribute__((ext_vector_type(4))) float float4v;
typedef __attribute__((ext_vector_type(4))) unsigned short ushort4v;
typedef unsigned int uint32;
typedef unsigned short ushort16;

// fp32 -> bf16 with round-half-up (cheap: add 0x8000, take hi16)
static __device__ __forceinline__ ushort16 f2bf(float v) {
  uint32 u = __builtin_bit_cast(uint32, v);
  return (ushort16)((u + 0x8000u) >> 16);
}

// ---------------------------------------------------------------------------
// Kernel 1: first/second moments of [x,y,z,||xyz||] (BN1 is linear in these).
// 128 blocks; wave shfl-reduce -> LDS block-reduce -> ONE atomic per scalar
// per block, each scalar in its own cache line. (Round-2 lesson: 28K atomics
// to one line = 369 us of pure serialization.)
// ---------------------------------------------------------------------------
#define MOMB 128  // blocks
__global__ __launch_bounds__(256) void k_xyz_moments(
    const float* __restrict__ gx, float* __restrict__ ws) {
  float s[14];
#pragma unroll
  for (int i = 0; i < 14; ++i) s[i] = 0.f;
  int tid = blockIdx.x * 256 + threadIdx.x;   // 0..32767
  const int nth = MOMB * 256;
  for (int p = tid; p < PTOT; p += nth) {
    int b = p >> 17;
    int r = p & (NKP - 1);
    const float* base = gx + (size_t)b * 3 * NKP + r;
    float v[4];
    v[0] = base[0];
    v[1] = base[NKP];
    v[2] = base[2 * NKP];
    v[3] = sqrtf(v[0] * v[0] + v[1] * v[1] + v[2] * v[2]);
#pragma unroll
    for (int j = 0; j < 4; ++j) s[j] += v[j];
    int idx = 4;
#pragma unroll
    for (int j = 0; j < 4; ++j)
#pragma unroll
      for (int l = j; l < 4; ++l) s[idx++] += v[j] * v[l];
  }
  // wave64 reduce each scalar
#pragma unroll
  for (int i = 0; i < 14; ++i) {
    float x = s[i];
#pragma unroll
    for (int off = 32; off > 0; off >>= 1) x += __shfl_down(x, off, 64);
    s[i] = x;
  }
  __shared__ float red[4][14];
  int wave = threadIdx.x >> 6;
  if ((threadIdx.x & 63) == 0) {
#pragma unroll
    for (int i = 0; i < 14; ++i) red[wave][i] = s[i];
  }
  __syncthreads();
  if (threadIdx.x < 14) {
    float v = red[0][threadIdx.x] + red[1][threadIdx.x] +
              red[2][threadIdx.x] + red[3][threadIdx.x];
    atomicAdd(&ws[WS_MOM + threadIdx.x * 16], v);
  }
}

// ---------------------------------------------------------------------------
// Kernel 2: transpose wb (64x512 fp32) -> wbT bf16 [col=512][ci=64] in ws.
// ---------------------------------------------------------------------------
__global__ __launch_bounds__(256) void k_wbt(const float* __restrict__ wb,
                                             ushort16* __restrict__ wbt) {
  int idx = blockIdx.x * 256 + threadIdx.x;  // 0..32767 = ci*512 + col
  int ci = idx >> 9;
  int col = idx & 511;
  wbt[col * 64 + ci] = f2bf(wb[idx]);
}

// ---------------------------------------------------------------------------
// Kernel 3: fold BN1 into alpha1/beta1 from the 14 moments.
// ---------------------------------------------------------------------------
__global__ void k_finalize1(const float* __restrict__ ws,
                            const float* __restrict__ w1,
                            const float* __restrict__ g1,
                            const float* __restrict__ b1,
                            float* __restrict__ out_ws) {
  int c = threadIdx.x;
  if (c >= HID) return;
  const float invP = 1.f / (float)PTOT;
  float mu[4];
#pragma unroll
  for (int j = 0; j < 4; ++j) mu[j] = ws[WS_MOM + j * 16] * invP;
  float S[4][4];
  int idx = 4;
#pragma unroll
  for (int j = 0; j < 4; ++j)
#pragma unroll
    for (int l = j; l < 4; ++l) {
      float v = ws[WS_MOM + idx * 16] * invP;
      ++idx;
      S[j][l] = v;
      S[l][j] = v;
    }
  float w[4];
#pragma unroll
  for (int j = 0; j < 4; ++j) w[j] = w1[c * 4 + j];
  float mean = 0.f;
#pragma unroll
  for (int j = 0; j < 4; ++j) mean += w[j] * mu[j];
  float Et2 = 0.f;
#pragma unroll
  for (int j = 0; j < 4; ++j)
#pragma unroll
    for (int l = 0; l < 4; ++l) Et2 += w[j] * w[l] * S[j][l];
  float var = Et2 - mean * mean;
  float a = g1[c] * rsqrtf(var + EPS);
  out_ws[WS_A1 + c] = a;
  out_ws[WS_B1 + c] = b1[c] - a * mean;
}

// ---------------------------------------------------------------------------
// Kernel 4: main MFMA kernel (unchanged from round 2).
// ---------------------------------------------------------------------------
#define PPB 128   // points per block
#define ROWA 68   // feat LDS row pitch (bf16 units; 136 B keeps b64 align)
#define ROWO 66   // out-stage LDS row pitch (floats)

__global__ __launch_bounds__(256, 3) void k_main_mfma(
    const float* __restrict__ gx, const float* __restrict__ feat,
    const float* __restrict__ w1, const float* __restrict__ w2,
    const float* __restrict__ b2, const ushort16* __restrict__ wbt,
    float* __restrict__ ws, float* __restrict__ out) {
  __shared__ char smem[35840];
  ushort16* fl = (ushort16*)smem;              // phase1: [128][ROWA] bf16
  float* scl = (float*)(smem + 17408);         // phase1: [128][8] scores
  float* outst = (float*)smem;                 // phase2: [128][ROWO] fp32
  float* sstat = (float*)(smem + 33792);       // phase2: [4][64]
  float* qstat = (float*)(smem + 34816);       // phase2: [4][64]

  const int t = threadIdx.x;
  const int pblk = blockIdx.x * PPB;
  const int b = pblk >> 17;
  const int r0 = pblk & (NKP - 1);

  // ---- Phase 1a: ScoreNet for the block's 128 points (threads 0..127)
  if (t < PPB) {
    int r = r0 + t;
    const float* gb = gx + (size_t)b * 3 * NKP + r;
    float x = gb[0], y = gb[NKP], z = gb[2 * NKP];
    float ed = sqrtf(x * x + y * y + z * z);
    float h[HID];
#pragma unroll
    for (int c = 0; c < HID; ++c) {
      float tv = w1[c * 4 + 0] * x + w1[c * 4 + 1] * y + w1[c * 4 + 2] * z +
                 w1[c * 4 + 3] * ed;
      h[c] = fmaxf(ws[WS_A1 + c] * tv + ws[WS_B1 + c], 0.f);
    }
    float s[PM];
#pragma unroll
    for (int m = 0; m < PM; ++m) {
      float a = b2[m];
#pragma unroll
      for (int c = 0; c < HID; ++c) a += w2[m * HID + c] * h[c];
      s[m] = a;
    }
    float mx = s[0];
#pragma unroll
    for (int m = 1; m < PM; ++m) mx = fmaxf(mx, s[m]);
    float esum = 0.f;
#pragma unroll
    for (int m = 0; m < PM; ++m) {
      s[m] = __expf(s[m] - mx);
      esum += s[m];
    }
    float inv = 1.f / (1.f + esum);
#pragma unroll
    for (int m = 0; m < PM; ++m) scl[t * 8 + m] = s[m] * inv;
  }

  // ---- Phase 1b: stage feat tile to LDS as bf16, transposed to [p][ci]
  {
    const float* fb = feat + (size_t)b * CIN * NKP + r0;
#pragma unroll
    for (int i = 0; i < 32; ++i) {
      int flat = i * 256 + t;
      int p = flat & (PPB - 1);
      int ci = flat >> 7;
      fl[p * ROWA + ci] = f2bf(fb[(size_t)ci * NKP + p]);
    }
  }
  __syncthreads();

  const int w = t >> 6;
  const int L = t & 63;
  const int l16 = L & 15;
  const int q4 = L >> 4;

  // preload f fragments (unpacked fp32 for cheap per-m scaling) + scores
  float ff[2][2][8];  // [rowtile][kstep][elem]
#pragma unroll
  for (int rt = 0; rt < 2; ++rt) {
    int p = w * 32 + rt * 16 + l16;
#pragma unroll
    for (int ks = 0; ks < 2; ++ks) {
      const ushort4v* a0 = (const ushort4v*)&fl[p * ROWA + ks * 32 + q4 * 8];
      ushort4v v0 = a0[0], v1 = a0[1];
#pragma unroll
      for (int j = 0; j < 4; ++j) {
        ff[rt][ks][j] = __builtin_bit_cast(float, (uint32)v0[j] << 16);
        ff[rt][ks][4 + j] = __builtin_bit_cast(float, (uint32)v1[j] << 16);
      }
    }
  }
  float4v scf[2][2];  // [rowtile][half]: 8 scores for this lane's row
#pragma unroll
  for (int rt = 0; rt < 2; ++rt) {
    int p = w * 32 + rt * 16 + l16;
    const float4v* sp = (const float4v*)&scl[p * 8];
    scf[rt][0] = sp[0];
    scf[rt][1] = sp[1];
  }

  float4v acc[2][4];
#pragma unroll
  for (int rt = 0; rt < 2; ++rt)
#pragma unroll
    for (int ct = 0; ct < 4; ++ct) acc[rt][ct] = (float4v)0.f;

  // ---- m loop: scale A by sc[p][m], MFMA against wbT m-slice
#pragma unroll
  for (int m = 0; m < PM; ++m) {
    short8 bf[2][4];  // [kstep][coltile]
#pragma unroll
    for (int ks = 0; ks < 2; ++ks)
#pragma unroll
      for (int ct = 0; ct < 4; ++ct) {
        int col = m * 64 + ct * 16 + l16;
        bf[ks][ct] = *(const short8*)(wbt + col * 64 + ks * 32 + q4 * 8);
      }
#pragma unroll
    for (int rt = 0; rt < 2; ++rt) {
      float sm = scf[rt][m >> 2][m & 3];
#pragma unroll
      for (int ks = 0; ks < 2; ++ks) {
        union { short8 v; uint32 u[4]; } au;
#pragma unroll
        for (int e = 0; e < 4; ++e) {
          uint32 u0 =
              __builtin_bit_cast(uint32, ff[rt][ks][2 * e] * sm) + 0x8000u;
          uint32 u1 =
              __builtin_bit_cast(uint32, ff[rt][ks][2 * e + 1] * sm) + 0x8000u;
          au.u[e] = __builtin_amdgcn_perm(u1, u0, 0x07060302u);
        }
#pragma unroll
        for (int ct = 0; ct < 4; ++ct)
          acc[rt][ct] = __builtin_amdgcn_mfma_f32_16x16x32_bf16(
              au.v, bf[ks][ct], acc[rt][ct], 0, 0, 0);
      }
    }
  }
  __syncthreads();  // all LDS phase-1 reads done; safe to overwrite with outst

  // ---- BN2 stats from accumulators (cols: lanes L, L^16, L^32, L^48 share c)
#pragma unroll
  for (int ct = 0; ct < 4; ++ct) {
    float s = 0.f, q = 0.f;
#pragma unroll
    for (int rt = 0; rt < 2; ++rt)
#pragma unroll
      for (int r = 0; r < 4; ++r) {
        float v = acc[rt][ct][r];
        s += v;
        q += v * v;
      }
    s += __shfl_xor(s, 16, 64);
    q += __shfl_xor(q, 16, 64);
    s += __shfl_xor(s, 32, 64);
    q += __shfl_xor(q, 32, 64);
    if (L < 16) {
      sstat[w * 64 + ct * 16 + L] = s;
      qstat[w * 64 + ct * 16 + L] = q;
    }
  }

  // ---- stage out tile [p][c] (C-layout: row=q4*4+r, col=l16)
#pragma unroll
  for (int rt = 0; rt < 2; ++rt)
#pragma unroll
    for (int ct = 0; ct < 4; ++ct) {
      int rowb = w * 32 + rt * 16 + q4 * 4;
      int col = ct * 16 + l16;
#pragma unroll
      for (int r = 0; r < 4; ++r)
        outst[(rowb + r) * ROWO + col] = acc[rt][ct][r];
    }
  __syncthreads();

  // ---- block stats reduce -> spread atomics
  if (t < COUT) {
    float s = sstat[t] + sstat[64 + t] + sstat[128 + t] + sstat[192 + t];
    float q = qstat[t] + qstat[64 + t] + qstat[128 + t] + qstat[192 + t];
    int slot = blockIdx.x & 31;
    atomicAdd(&ws[WS_PSUM + slot * 64 + t], s);
    atomicAdd(&ws[WS_PSQ + slot * 64 + t], q);
  }

  // ---- coalesced global write of pre-BN out
  float* ob = out + (size_t)b * COUT * NKP + r0;
#pragma unroll
  for (int i = 0; i < 32; ++i) {
    int flat = i * 256 + t;
    int p = flat & (PPB - 1);
    int c = flat >> 7;
    ob[(size_t)c * NKP + p] = outst[p * ROWO + c];
  }
}

// ---------------------------------------------------------------------------
// Kernel 5: fold BN2 (reduce the 32 partial slots).
// ---------------------------------------------------------------------------
__global__ void k_finalize2(const float* __restrict__ ws,
                            const float* __restrict__ g_out,
                            const float* __restrict__ b_out,
                            float* __restrict__ out_ws) {
  int c = threadIdx.x;
  if (c >= COUT) return;
  float s = 0.f, q = 0.f;
  for (int sl = 0; sl < 32; ++sl) {
    s += ws[WS_PSUM + sl * 64 + c];
    q += ws[WS_PSQ + sl * 64 + c];
  }
  const float invP = 1.f / (float)PTOT;
  float mean = s * invP;
  float var = q * invP - mean * mean;
  float a = g_out[c] * rsqrtf(var + EPS);
  out_ws[WS_A2 + c] = a;
  out_ws[WS_B2 + c] = b_out[c] - a * mean;
}

// ---------------------------------------------------------------------------
// Kernel 6: in-place normalize + ReLU.
// ---------------------------------------------------------------------------
__global__ __launch_bounds__(256) void k_norm(float* __restrict__ out,
                                              const float* __restrict__ ws) {
  size_t i4 = (size_t)blockIdx.x * 256 + threadIdx.x;
  size_t elem = i4 * 4;
  int c = (int)((elem >> 17) & 63);
  float a = ws[WS_A2 + c];
  float bb = ws[WS_B2 + c];
  float4* p = (float4*)out;
  float4 v = p[i4];
  v.x = fmaxf(a * v.x + bb, 0.f);
  v.y = fmaxf(a * v.y + bb, 0.f);
  v.z = fmaxf(a * v.z + bb, 0.f);
  v.w = fmaxf(a * v.w + bb, 0.f);
  p[i4] = v;
}

extern "C" void kernel_launch(void* const* d_in, const int* in_sizes, int n_in,
                              void* d_out, int out_size, void* d_ws,
                              size_t ws_size, hipStream_t stream) {
  const float* gx = (const float*)d_in[0];
  const float* feat = (const float*)d_in[1];
  const float* w1 = (const float*)d_in[2];
  const float* g1 = (const float*)d_in[3];
  const float* b1 = (const float*)d_in[4];
  const float* w2 = (const float*)d_in[5];
  const float* b2 = (const float*)d_in[6];
  const float* wb = (const float*)d_in[7];
  const float* g_out = (const float*)d_in[8];
  const float* b_out = (const float*)d_in[9];
  float* out = (float*)d_out;
  float* ws = (float*)d_ws;
  ushort16* wbt = (ushort16*)(ws + WS_WBT);

  (void)in_sizes; (void)n_in; (void)out_size; (void)ws_size;

  hipMemsetAsync(d_ws, 0, WS_ZERO_FLOATS * sizeof(float), stream);

  k_xyz_moments<<<MOMB, 256, 0, stream>>>(gx, ws);
  k_wbt<<<128, 256, 0, stream>>>(wb, wbt);
  k_finalize1<<<1, 64, 0, stream>>>(ws, w1, g1, b1, ws);
  k_main_mfma<<<PTOT / PPB, 256, 0, stream>>>(gx, feat, w1, w2, b2, wbt, ws,
                                              out);
  k_finalize2<<<1, 64, 0, stream>>>(ws, g_out, b_out, ws);
  k_norm<<<(PTOT * COUT / 4) / 256, 256, 0, stream>>>(out, ws);
}